// Round 4
// baseline (436.929 us; speedup 1.0000x reference)
//
#include <hip/hip_runtime.h>

// 2-level inverse Haar DWT, fully fused, v3 (v2 + native vector types for
// __builtin_nontemporal_* — HIP_vector_type float4 is a class and is rejected).
// yl (16,64,64,64), yh0 (16,64,3,128,128), yh1 (16,64,3,64,64) -> out (16,64,256,256), fp32.
//
// Haar k=2 stride-2 transposed conv = non-overlapping 2x2 butterflies:
//   out[2p+da][2m+db] = 0.5*(LL[p][m] + sda*LH[p][m] + sdb*HL[p][m] + sda*sdb*HH[p][m])
// chained over 2 levels. Each thread: 1 coarse row i, mid-row parity a, 2 coarse
// cols (j0, j0+1) -> 2 output rows x 8 cols = 16 outputs.
//
// Wave layout (tid&63): lanes 0..31 a=0, lanes 32..63 a=1, jh=tid&31.
//  - yh0 vfloat4 load: lanes 0..31 cover mid row 2i (512B), lanes 32..63 row 2i+1
//    -> one contiguous 1KB segment per wave per subband. Nontemporal (streaming).
//  - yl/yh1 vfloat2 loads: both half-waves issue identical addresses in the SAME
//    instruction -> coalescer fetches 256B once, broadcasts.
//  - stores: 2x nontemporal vfloat4 per row, half-wave = 512B contiguous segment.

typedef float vfloat4 __attribute__((ext_vector_type(4)));
typedef float vfloat2 __attribute__((ext_vector_type(2)));

#define NC_TOT 1024        // N*C = 16*64
#define HC 64              // coarse H=W
#define HM 128             // mid (level-1 output) H=W
#define HO 256             // final output H=W

__global__ __launch_bounds__(256) void idwt2_haar_fused_v3(
    const float* __restrict__ yl,
    const float* __restrict__ yh0,
    const float* __restrict__ yh1,
    float* __restrict__ out)
{
    const int tid = threadIdx.x;
    const int jh  = tid & 31;          // coarse col-pair index: cols 2jh, 2jh+1
    const int a   = (tid >> 5) & 1;    // mid-row parity
    const int il  = tid >> 6;          // 0..3
    const int blk = blockIdx.x;        // 0 .. NC_TOT*16-1
    const int nc  = blk >> 4;
    const int i   = ((blk & 15) << 2) + il;   // coarse row 0..63

    const vfloat2* __restrict__ yl2  = (const vfloat2*)yl;
    const vfloat2* __restrict__ yh12 = (const vfloat2*)yh1;
    const vfloat4* __restrict__ yh04 = (const vfloat4*)yh0;
    vfloat4* __restrict__ outv = (vfloat4*)out;

    // ---- level-1 inputs: vfloat2 at coarse (i, 2jh..2jh+1) ----
    const vfloat2 ll2 = yl2[(nc * HC + i) * (HC / 2) + jh];
    const int b1 = ((nc * 3) * HC + i) * (HC / 2) + jh;   // yh1 subband stride = HC*HC/2 vfloat2
    const vfloat2 lh2 = yh12[b1];
    const vfloat2 hl2 = yh12[b1 + HC * HC / 2];
    const vfloat2 hh2 = yh12[b1 + 2 * (HC * HC / 2)];

    // ---- level-1 butterfly for this thread's mid-row parity a ----
    const float sa = a ? -1.0f : 1.0f;
    const float ex = ll2.x + sa * lh2.x, fx = hl2.x + sa * hh2.x;
    const float ey = ll2.y + sa * lh2.y, fy = hl2.y + sa * hh2.y;
    // LL1 at mid row p=2i+a, mid cols 4jh..4jh+3
    float LL[4];
    LL[0] = 0.5f * (ex + fx);
    LL[1] = 0.5f * (ex - fx);
    LL[2] = 0.5f * (ey + fy);
    LL[3] = 0.5f * (ey - fy);

    // ---- level-0 inputs: yh0 vfloat4 at mid row p, mid cols 4jh..4jh+3 ----
    const int p  = 2 * i + a;
    const int b0 = ((nc * 3) * HM + p) * (HM / 4) + jh;   // subband stride = HM*HM/4 vfloat4
    const vfloat4 LH = __builtin_nontemporal_load(yh04 + b0);
    const vfloat4 HL = __builtin_nontemporal_load(yh04 + b0 + HM * HM / 4);
    const vfloat4 HH = __builtin_nontemporal_load(yh04 + b0 + 2 * (HM * HM / 4));

    // ---- level-0 butterfly: output rows 2p+da, cols 8jh..8jh+7 ----
    #pragma unroll
    for (int da = 0; da < 2; ++da) {
        const float sd = da ? -1.0f : 1.0f;
        vfloat4 o0, o1;
        {
            const float e0 = LL[0] + sd * LH.x, f0 = HL.x + sd * HH.x;
            const float e1 = LL[1] + sd * LH.y, f1 = HL.y + sd * HH.y;
            o0.x = 0.5f * (e0 + f0);
            o0.y = 0.5f * (e0 - f0);
            o0.z = 0.5f * (e1 + f1);
            o0.w = 0.5f * (e1 - f1);
        }
        {
            const float e2 = LL[2] + sd * LH.z, f2 = HL.z + sd * HH.z;
            const float e3 = LL[3] + sd * LH.w, f3 = HL.w + sd * HH.w;
            o1.x = 0.5f * (e2 + f2);
            o1.y = 0.5f * (e2 - f2);
            o1.z = 0.5f * (e3 + f3);
            o1.w = 0.5f * (e3 - f3);
        }
        const int r  = 4 * i + 2 * a + da;                 // output row
        const int ob = (nc * HO + r) * (HO / 4) + 2 * jh;  // vfloat4 index
        __builtin_nontemporal_store(o0, outv + ob);
        __builtin_nontemporal_store(o1, outv + ob + 1);
    }
}

extern "C" void kernel_launch(void* const* d_in, const int* in_sizes, int n_in,
                              void* d_out, int out_size, void* d_ws, size_t ws_size,
                              hipStream_t stream) {
    const float* yl  = (const float*)d_in[0];
    const float* yh0 = (const float*)d_in[1];
    const float* yh1 = (const float*)d_in[2];
    // d_in[3] = filts, hardcoded (Haar: all taps +/- 1/sqrt(2); (1/sqrt(2))^2 = 0.5)
    float* out = (float*)d_out;

    const int blocks = NC_TOT * 16;   // 16384 blocks x 256 threads, 16 outputs/thread
    idwt2_haar_fused_v3<<<blocks, 256, 0, stream>>>(yl, yh0, yh1, out);
}